// Round 7
// baseline (25.508 us; speedup 1.0000x reference)
//
#include <hip/hip_runtime.h>

// Post_process_deconv: out = depth + b + sum_k w[k] * (weight[k] - mean_k(weight)) *
//                           bilinear(depth, y - 1 + kh + dy_k, x - 1 + kw + dx_k)
// Shapes: depth [B,1,H,W], weight [B,9,H,W], offset [B,18,H,W], w [1,1,3,3], b [1]
// B=2, H=352, W=1216, K=3, pad=1. All fp32.
//
// Round 7: keep round-6's LDS-served gathers (cheap pipe), halve the dominant
// streaming instruction count by processing TWO x-adjacent pixels per thread:
// each weight/offset plane load is one float2 (dwordx2). Block = 64x8 px tile,
// 256 threads, grid 1672. Residual depth read from LDS. Mean-subtraction uses
// the identity sum wk*(wv-m)*s = sum wk*wv*s - m*sum wk*s so wmean is applied
// once at the end.

#define KK 3
#define K2 9
#define PAD 1
#define BB 2
#define HH 352
#define WW 1216

#define TX 64                       // tile width in px
#define TY 8                        // tile height in px
#define NTX (WW / TX)               // 19
#define NTY (HH / TY)               // 44
#define HALO 7
#define SROWS (TY + 2 * HALO + 1)   // 23
#define SCOLS (TX + 2 * HALO + 2)   // 80

__global__ __launch_bounds__(256) void ppd_kernel(
    const float* __restrict__ depth,   // [B, H*W]
    const float* __restrict__ weight,  // [B, 9, H*W]
    const float* __restrict__ offset,  // [B, 18, H*W]
    const float* __restrict__ wk,      // [9]
    const float* __restrict__ bias,    // [1]
    float* __restrict__ out)           // [B, H*W]
{
    constexpr int HW  = HH * WW;
    constexpr int HW2 = HW / 2;

    __shared__ float sd[SROWS * SCOLS];   // 7360 B

    const int bid = blockIdx.x;
    const int b   = bid / (NTY * NTX);
    const int rem = bid - b * (NTY * NTX);
    const int ty  = rem / NTX;
    const int tx  = rem - ty * NTX;

    const int tid  = threadIdx.x;
    const int pcol = tid & 31;            // pair column 0..31
    const int prow = tid >> 5;            // row 0..7
    const int x    = tx * TX + pcol * 2;  // even
    const int y    = ty * TY + prow;

    const float* dimg = depth + (size_t)b * HW;
    const int base_y = ty * TY - HALO;
    const int base_x = tx * TX - HALO;

    // ---- stage depth tile into LDS (zero-filled outside image) ----
    for (int t = tid; t < SROWS * SCOLS; t += 256) {
        const int r  = t / SCOLS;
        const int c  = t - r * SCOLS;
        const int gy = base_y + r;
        const int gx = base_x + c;
        float v = 0.f;
        if ((unsigned)gy < (unsigned)HH && (unsigned)gx < (unsigned)WW)
            v = dimg[gy * WW + gx];
        sd[t] = v;
    }

    // ---- streaming plane loads: one float2 per plane per thread ----
    const int hw  = y * WW + x;           // even
    const int hw2 = hw >> 1;
    const float2* wgt2 = reinterpret_cast<const float2*>(weight + (size_t)b * (K2 * HW)) + hw2;
    const float2* off2 = reinterpret_cast<const float2*>(offset + (size_t)b * (2 * K2 * HW)) + hw2;

    float2 wv2[K2], dy2[K2], dx2[K2];
#pragma unroll
    for (int k = 0; k < K2; ++k) wv2[k] = wgt2[(size_t)k * HW2];
#pragma unroll
    for (int k = 0; k < K2; ++k) {
        dy2[k] = off2[(size_t)(2 * k)     * HW2];
        dx2[k] = off2[(size_t)(2 * k + 1) * HW2];
    }

    __syncthreads();

    float A[2]  = {0.f, 0.f};   // sum_k wk*wv*s
    float S[2]  = {0.f, 0.f};   // sum_k wk*s
    float ws[2] = {0.f, 0.f};   // sum_k wv

#pragma unroll
    for (int k = 0; k < K2; ++k) {
        const int kh = k / KK;
        const int kw = k - kh * KK;
        const float wkk = wk[k];          // uniform

        const float wvv[2] = {wv2[k].x, wv2[k].y};
        const float dyv[2] = {dy2[k].x, dy2[k].y};
        const float dxv[2] = {dx2[k].x, dx2[k].y};

#pragma unroll
        for (int j = 0; j < 2; ++j) {
            const float py = (float)(y - PAD + kh) + dyv[j];
            const float px = (float)(x + j - PAD + kw) + dxv[j];

            const float y0f = floorf(py);
            const float x0f = floorf(px);
            const float fy = py - y0f;
            const float fx = px - x0f;
            const int y0 = (int)y0f;
            const int x0 = (int)x0f;

            const int lr = y0 - base_y;   // want [0, SROWS-2]
            const int lc = x0 - base_x;   // want [0, SCOLS-2]

            float s;
            if (__builtin_expect((unsigned)lr <= (unsigned)(SROWS - 2) &&
                                 (unsigned)lc <= (unsigned)(SCOLS - 2), 1)) {
                const float* r0 = &sd[lr * SCOLS + lc];
                const float v00 = r0[0];
                const float v01 = r0[1];
                const float v10 = r0[SCOLS];
                const float v11 = r0[SCOLS + 1];
                s = (1.f - fy) * ((1.f - fx) * v00 + fx * v01)
                  + fy         * ((1.f - fx) * v10 + fx * v11);
            } else {
                // rare fallback: global clamped loads + validity-folded weights
                const float wy0 = ((unsigned)y0       < (unsigned)HH) ? (1.f - fy) : 0.f;
                const float wy1 = ((unsigned)(y0 + 1) < (unsigned)HH) ? fy         : 0.f;
                const float wx0 = ((unsigned)x0       < (unsigned)WW) ? (1.f - fx) : 0.f;
                const float wx1 = ((unsigned)(x0 + 1) < (unsigned)WW) ? fx         : 0.f;
                const int y0c = min(max(y0, 0), HH - 1);
                const int y1c = min(max(y0 + 1, 0), HH - 1);
                const int x0c = min(max(x0, 0), WW - 1);
                const int x1c = min(max(x0 + 1, 0), WW - 1);
                const float v00 = dimg[y0c * WW + x0c];
                const float v01 = dimg[y0c * WW + x1c];
                const float v10 = dimg[y1c * WW + x0c];
                const float v11 = dimg[y1c * WW + x1c];
                s = wy0 * (wx0 * v00 + wx1 * v01)
                  + wy1 * (wx0 * v10 + wx1 * v11);
            }

            const float t = wkk * s;
            A[j]  = fmaf(t, wvv[j], A[j]);
            S[j] += t;
            ws[j] += wvv[j];
        }
    }

    // residual from LDS; epilogue
    const int lrr = y - base_y;
    const int lcc = x - base_x;
    const float bb = bias[0];
    float o[2];
#pragma unroll
    for (int j = 0; j < 2; ++j) {
        const float dres  = sd[lrr * SCOLS + lcc + j];
        const float wmean = ws[j] * (1.0f / 9.0f);
        o[j] = fmaf(-wmean, S[j], A[j]) + bb + dres;
    }
    *reinterpret_cast<float2*>(out + (size_t)b * HW + hw) = make_float2(o[0], o[1]);
}

extern "C" void kernel_launch(void* const* d_in, const int* in_sizes, int n_in,
                              void* d_out, int out_size, void* d_ws, size_t ws_size,
                              hipStream_t stream) {
    const float* depth  = (const float*)d_in[0];
    const float* weight = (const float*)d_in[1];
    const float* offset = (const float*)d_in[2];
    const float* wk     = (const float*)d_in[3];
    const float* bias   = (const float*)d_in[4];
    float* out = (float*)d_out;

    const int grid = BB * NTY * NTX;   // 1672
    ppd_kernel<<<grid, 256, 0, stream>>>(depth, weight, offset, wk, bias, out);
}